// Round 6
// baseline (333.321 us; speedup 1.0000x reference)
//
#include <hip/hip_runtime.h>

typedef __bf16 bf16;
typedef __bf16 bf16x8 __attribute__((ext_vector_type(8)));
typedef __bf16 bf16x4 __attribute__((ext_vector_type(4)));
typedef _Float16 f16x4 __attribute__((ext_vector_type(4)));
typedef _Float16 f16x8 __attribute__((ext_vector_type(8)));
typedef float  f32x4  __attribute__((ext_vector_type(4)));

#define LOG2E 1.44269504088896340736f
#define SCQ (0.125f * LOG2E)

__device__ __forceinline__ void async16(const void* g, void* l) {
  __builtin_amdgcn_global_load_lds(
      (const __attribute__((address_space(1))) unsigned int*)g,
      (__attribute__((address_space(3))) unsigned int*)l, 16, 0, 0);
}

__device__ __forceinline__ f32x4 mfma_bf16(bf16x8 a, bf16x8 b, f32x4 c) {
  return __builtin_amdgcn_mfma_f32_16x16x32_bf16(a, b, c, 0, 0, 0);
}
__device__ __forceinline__ f32x4 mfma_f16k16(f16x4 a, f16x4 b, f32x4 c) {
  return __builtin_amdgcn_mfma_f32_16x16x16f16(a, b, c, 0, 0, 0);
}

// ---------------- fp32 -> bf16 convert, all 3 activations in one launch --------
__global__ __launch_bounds__(256) void cvt3(const float* __restrict__ q,
                                            const float* __restrict__ k,
                                            const float* __restrict__ v,
                                            bf16* __restrict__ out) {
  int z = blockIdx.y;
  const float* in = z == 0 ? q : (z == 1 ? k : v);
  bf16* o = out + (size_t)z * 8388608;
  int i = blockIdx.x * 256 + threadIdx.x;
  const float4* p = (const float4*)in;
  float4 a = p[i * 2], c = p[i * 2 + 1];
  bf16x8 r;
  r[0] = (bf16)a.x; r[1] = (bf16)a.y; r[2] = (bf16)a.z; r[3] = (bf16)a.w;
  r[4] = (bf16)c.x; r[5] = (bf16)c.y; r[6] = (bf16)c.z; r[7] = (bf16)c.w;
  ((bf16x8*)o)[i] = r;
}

// ---------------- weight transpose: W[k][n] f32 -> Wt[n][k] bf16 ----------------
__global__ __launch_bounds__(256) void wtrans(const float* __restrict__ W0,
                                              const float* __restrict__ W1,
                                              const float* __restrict__ W2,
                                              bf16* __restrict__ Wt) {
  const float* W = blockIdx.z == 0 ? W0 : (blockIdx.z == 1 ? W1 : W2);
  bf16* O = Wt + (size_t)blockIdx.z * (1024 * 1024);
  __shared__ float t[64 * 69];
  int tid = threadIdx.x;
  int k0 = blockIdx.x * 64, n0 = blockIdx.y * 64;
  int r0 = tid >> 4, c0 = (tid & 15) * 4;
#pragma unroll
  for (int rr = 0; rr < 4; rr++) {
    int k = r0 + rr * 16;
    float4 v = *(const float4*)(W + (k0 + k) * 1024 + n0 + c0);
    t[k * 69 + c0 + 0] = v.x; t[k * 69 + c0 + 1] = v.y;
    t[k * 69 + c0 + 2] = v.z; t[k * 69 + c0 + 3] = v.w;
  }
  __syncthreads();
#pragma unroll
  for (int rr = 0; rr < 4; rr++) {
    int n = r0 + rr * 16;
    bf16x4 o;
#pragma unroll
    for (int j = 0; j < 4; j++) o[j] = (bf16)t[(c0 + j) * 69 + n];
    *(bf16x4*)(O + (n0 + n) * 1024 + k0 + c0) = o;
  }
}

// ---------------- batched projection GEMM, tile 128x256 (r4 two-barrier) --------
// z=0: qo = (A*Wq+bq)*SCQ bf16 [m][n]; z=1: ko = A*Wk+bk bf16 [m][n];
// z=2: vf = A*Wv+bv f16, paired PV-fragment order:
//      vf[(((b*16+h)*32+kvb64)*8 + (mt*2+np))*64 + lane][8] ; element (kv,d):
//      kvb64=kv>>6, mt=(kv>>4)&3, lane=((kv>>2)&3)*16+(d&15),
//      half-slot = ((d>>4)&1)*4 + (kv&3), np=(d>>5)&1.
__global__ __launch_bounds__(256, 2) void gemm_qkv(const bf16* __restrict__ Act,
                                                   const bf16* __restrict__ Wt,
                                                   const float* __restrict__ b0,
                                                   const float* __restrict__ b1,
                                                   const float* __restrict__ b2,
                                                   bf16* __restrict__ qo,
                                                   bf16* __restrict__ ko,
                                                   _Float16* __restrict__ vf) {
  __shared__ bf16 smem[24576];          // sA 128x64 (16KB) | sB 256x64 (32KB)
  bf16* sA = smem;
  bf16* sB = smem + 8192;
  const int tid = threadIdx.x;
  const int wave = tid >> 6, lane = tid & 63;
  const int quad = lane >> 4, l15 = lane & 15;
  const int z = blockIdx.z;
  const int lin = blockIdx.y * 64 + blockIdx.x;     // 0..255 within z
  const int tx = (lin & 7) | ((lin >> 5) << 3);     // 0..63  (m-block)
  const int ty = (lin >> 3) & 3;                    // 0..3   (n-block)
  const int m0 = tx * 128, n0 = ty * 256;
  const bf16* A = Act + (size_t)z * 8388608;
  const bf16* Bt = Wt + (size_t)z * 1048576;
  const float* bias = z == 0 ? b0 : (z == 1 ? b1 : b2);

  const bf16* ap[4]; int loa[4];
  const bf16* bp[8]; int lob[8];
#pragma unroll
  for (int i = 0; i < 4; i++) {
    int g = wave * 256 + i * 64 + lane;
    int row = g >> 3, jl = (g & 7) ^ (row & 7);
    ap[i] = A + (m0 + row) * 1024 + jl * 8;
    loa[i] = (wave * 256 + i * 64) * 8;
  }
#pragma unroll
  for (int i = 0; i < 8; i++) {
    int g = wave * 512 + i * 64 + lane;
    int row = g >> 3, jl = (g & 7) ^ (row & 7);
    bp[i] = Bt + (n0 + row) * 1024 + jl * 8;
    lob[i] = (wave * 512 + i * 64) * 8;
  }
  const int wm = (wave & 1) * 64, wn = (wave >> 1) * 128;
  f32x4 acc[4][8] = {};

  for (int kt = 0; kt < 16; kt++) {
    const int ko_ = kt * 64;
#pragma unroll
    for (int i = 0; i < 4; i++) async16(ap[i] + ko_, sA + loa[i]);
#pragma unroll
    for (int i = 0; i < 8; i++) async16(bp[i] + ko_, sB + lob[i]);
    __syncthreads();
#pragma unroll
    for (int ks = 0; ks < 2; ks++) {
      bf16x8 af[4];
#pragma unroll
      for (int mt = 0; mt < 4; mt++) {
        int m = wm + mt * 16 + l15;
        int ph = (ks * 4 + quad) ^ (m & 7);
        af[mt] = *(const bf16x8*)(sA + m * 64 + ph * 8);
      }
#pragma unroll
      for (int nh = 0; nh < 2; nh++) {
        bf16x8 bv[4];
#pragma unroll
        for (int nt = 0; nt < 4; nt++) {
          int n = wn + (nh * 4 + nt) * 16 + l15;
          int ph = (ks * 4 + quad) ^ (n & 7);
          bv[nt] = *(const bf16x8*)(sB + n * 64 + ph * 8);
        }
#pragma unroll
        for (int mt = 0; mt < 4; mt++)
#pragma unroll
          for (int nt = 0; nt < 4; nt++)
            acc[mt][nh * 4 + nt] = mfma_bf16(af[mt], bv[nt], acc[mt][nh * 4 + nt]);
      }
    }
    __syncthreads();
  }

  if (z != 2) {
    bf16* O = z == 0 ? qo : ko;
    const float sc = z == 0 ? SCQ : 1.0f;
#pragma unroll
    for (int nt = 0; nt < 8; nt++) {
      int n = n0 + wn + nt * 16 + l15;
      float bc = bias[n];
#pragma unroll
      for (int mt = 0; mt < 4; mt++)
#pragma unroll
        for (int r = 0; r < 4; r++) {
          int m = m0 + wm + mt * 16 + quad * 4 + r;
          O[m * 1024 + n] = (bf16)((acc[mt][nt][r] + bc) * sc);
        }
    }
  } else {
    // paired fragment-order stores: {acc[mt][2k], acc[mt][2k+1]} -> one f16x8
    const int b = m0 >> 11, s0 = m0 & 2047;
    const int kvb64 = (s0 + wm) >> 6;    // mt = kv-16-group, r = kv&3, quad = (kv>>2)&3
#pragma unroll
    for (int k2 = 0; k2 < 4; k2++) {
      int nn = n0 + wn + k2 * 32;        // 32-aligned: h fixed, dt = {2np,2np+1}
      int h = nn >> 6, np = (nn >> 5) & 1;
      float bc0 = bias[nn + l15];
      float bc1 = bias[nn + 16 + l15];
#pragma unroll
      for (int mt = 0; mt < 4; mt++) {
        f16x8 pk;
#pragma unroll
        for (int r = 0; r < 4; r++) {
          pk[r]     = (_Float16)(acc[mt][2 * k2][r] + bc0);
          pk[4 + r] = (_Float16)(acc[mt][2 * k2 + 1][r] + bc1);
        }
        size_t off = ((((size_t)(b * 16 + h) * 32 + kvb64) * 8 + (mt * 2 + np)) * 64 + lane) * 8;
        *(f16x8*)(vf + off) = pk;
      }
    }
  }
}

// ---------------- flash attention, S^T trick, KV-tile 64, dbuf + explicit drain -
// Q pre-scaled bf16 [B,S,1024]; K bf16 [B,S,1024]; VF f16 paired-fragment order;
// Out fp32 [B,S,1024]. Q-tile 128 (wave owns 32 q). 48 KB LDS -> 3 blocks/CU.
// Race fix vs r5: explicit s_waitcnt(0) BEFORE the barrier guarantees the
// in-flight LDS-DMA prefetch is drained (aged by the whole compute phase).
__global__ __launch_bounds__(256, 4) void attn(const bf16* __restrict__ Q,
                                               const bf16* __restrict__ K,
                                               const _Float16* __restrict__ VF,
                                               float* __restrict__ Out) {
  __shared__ bf16 sQ[8192];            // 128 x 64 (16 KB)
  __shared__ bf16 sK[2][4096];         // 64 x 64 per buf (16 KB)
  __shared__ _Float16 sV[2][4096];     // paired fragment order per buf (16 KB)
  const int tid = threadIdx.x;
  const int wave = tid >> 6, lane = tid & 63;
  const int quad = lane >> 4, l15 = lane & 15;
  const int q0 = blockIdx.x * 128, h = blockIdx.y, b = blockIdx.z;
  const bf16* Kbase = K + (size_t)(b * 2048) * 1024 + h * 64;
  const _Float16* Vbase = VF + (size_t)(b * 16 + h) * 131072;

  // stage Q + K/V block 0 (issue -> barrier: proven-safe pattern)
#pragma unroll
  for (int i = 0; i < 4; i++) {
    int g = i * 256 + tid;
    int row = g >> 3, jl = (g & 7) ^ (row & 7);
    async16(Q + (size_t)(b * 2048 + q0 + row) * 1024 + h * 64 + jl * 8, sQ + g * 8);
  }
#pragma unroll
  for (int i = 0; i < 2; i++) {
    int g = i * 256 + tid;
    int row = g >> 3, jl = (g & 7) ^ (row & 7);
    async16(Kbase + (size_t)row * 1024 + jl * 8, sK[0] + g * 8);
    async16(Vbase + g * 8, sV[0] + g * 8);
  }
  __syncthreads();

  // Q fragments (B-operand: lane=q, k=quad*8+j), wave owns q rows wave*32..+31
  bf16x8 qf[2][2];
#pragma unroll
  for (int qt2 = 0; qt2 < 2; qt2++)
#pragma unroll
    for (int ks = 0; ks < 2; ks++) {
      int m = wave * 32 + qt2 * 16 + l15;
      int ph = (ks * 4 + quad) ^ (l15 & 7);
      qf[qt2][ks] = *(const bf16x8*)(sQ + m * 64 + ph * 8);
    }

  f32x4 oaccT[2][4] = {};    // [qt2][dt] : O^T tile, row=d(quad*4+r), col=q(l15)
  float ls[2] = {0.f, 0.f};
  const int ph0 = quad ^ (l15 & 7), ph1 = (4 + quad) ^ (l15 & 7);

  for (int kvb = 0; kvb < 32; kvb++) {
    const int cur = kvb & 1;
    // issue next K/V prefetch FIRST; drained explicitly after compute
    if (kvb < 31) {
      int kn = (kvb + 1) * 64;
      bf16* dK = sK[cur ^ 1];
      _Float16* dV = sV[cur ^ 1];
#pragma unroll
      for (int i = 0; i < 2; i++) {
        int g = i * 256 + tid;
        int row = g >> 3, jl = (g & 7) ^ (row & 7);
        async16(Kbase + (size_t)(kn + row) * 1024 + jl * 8, dK + g * 8);
        async16(Vbase + (kvb + 1) * 4096 + g * 8, dV + g * 8);
      }
    }
    const bf16* sKc = sK[cur];
    const _Float16* sVc = sV[cur];
#pragma unroll
    for (int t = 0; t < 4; t++) {
      int row = t * 16 + l15;
      bf16x8 kf0 = *(const bf16x8*)(sKc + row * 64 + ph0 * 8);
      bf16x8 kf1 = *(const bf16x8*)(sKc + row * 64 + ph1 * 8);
      f32x4 st0 = {}, st1 = {};
      st0 = mfma_bf16(kf0, qf[0][0], st0);
      st0 = mfma_bf16(kf1, qf[0][1], st0);
      st1 = mfma_bf16(kf0, qf[1][0], st1);
      st1 = mfma_bf16(kf1, qf[1][1], st1);
      f16x4 pf0, pf1;
#pragma unroll
      for (int r = 0; r < 4; r++) {
        float p0 = __builtin_amdgcn_exp2f(st0[r]);
        float p1 = __builtin_amdgcn_exp2f(st1[r]);
        ls[0] += p0; ls[1] += p1;
        pf0[r] = (_Float16)p0; pf1[r] = (_Float16)p1;
      }
      const _Float16* sVt = sVc + t * 1024;
#pragma unroll
      for (int np = 0; np < 2; np++) {
        f16x8 va2 = *(const f16x8*)(sVt + np * 512 + lane * 8);
        f16x4 lo = __builtin_shufflevector(va2, va2, 0, 1, 2, 3);
        f16x4 hi = __builtin_shufflevector(va2, va2, 4, 5, 6, 7);
        oaccT[0][2 * np]     = mfma_f16k16(lo, pf0, oaccT[0][2 * np]);
        oaccT[0][2 * np + 1] = mfma_f16k16(hi, pf0, oaccT[0][2 * np + 1]);
        oaccT[1][2 * np]     = mfma_f16k16(lo, pf1, oaccT[1][2 * np]);
        oaccT[1][2 * np + 1] = mfma_f16k16(hi, pf1, oaccT[1][2 * np + 1]);
      }
    }
    if (kvb < 31) {
      __builtin_amdgcn_s_waitcnt(0);   // drain aged LDS-DMA before the barrier
      __syncthreads();
    }
  }

  // ---- epilogue: reduce l across quads, scale, store fp32 ----
#pragma unroll
  for (int qt2 = 0; qt2 < 2; qt2++) {
    float l = ls[qt2];
    l += __shfl_xor(l, 16);
    l += __shfl_xor(l, 32);
    float inv = 1.f / l;
    int qrow = b * 2048 + q0 + wave * 32 + qt2 * 16 + l15;
#pragma unroll
    for (int dt = 0; dt < 4; dt++) {
      float4 v;
      v.x = oaccT[qt2][dt][0] * inv;
      v.y = oaccT[qt2][dt][1] * inv;
      v.z = oaccT[qt2][dt][2] * inv;
      v.w = oaccT[qt2][dt][3] * inv;
      *(float4*)(Out + (size_t)qrow * 1024 + h * 64 + dt * 16 + quad * 4) = v;
    }
  }
}

extern "C" void kernel_launch(void* const* d_in, const int* in_sizes, int n_in,
                              void* d_out, int out_size, void* d_ws, size_t ws_size,
                              hipStream_t stream) {
  const float* key   = (const float*)d_in[0];
  const float* value = (const float*)d_in[1];
  const float* query = (const float*)d_in[2];
  const float* Wq = (const float*)d_in[3];
  const float* bq = (const float*)d_in[4];
  const float* Wk = (const float*)d_in[5];
  const float* bk = (const float*)d_in[6];
  const float* Wv = (const float*)d_in[7];
  const float* bv = (const float*)d_in[8];
  float* out = (float*)d_out;

  char* ws = (char*)d_ws;
  bf16* actb   = (bf16*)(ws);                       // 48 MB: [query|key|value] bf16
  bf16* wt     = (bf16*)(ws + 50331648);            // 6 MB: Wq^T,Wk^T,Wv^T
  bf16* qo     = (bf16*)(ws + 56623104);            // 16 MB (pre-scaled)
  bf16* ko     = (bf16*)(ws + 73400320);            // 16 MB
  _Float16* vf = (_Float16*)(ws + 90177536);        // 16 MB paired-fragment order
  (void)in_sizes; (void)n_in; (void)out_size; (void)ws_size;

  wtrans<<<dim3(16, 16, 3), 256, 0, stream>>>(Wq, Wk, Wv, wt);
  cvt3<<<dim3(4096, 3), 256, 0, stream>>>(query, key, value, actb);
  gemm_qkv<<<dim3(64, 4, 3), 256, 0, stream>>>(actb, wt, bq, bk, bv, qo, ko, vf);
  attn<<<dim3(16, 16, 4), 256, 0, stream>>>(qo, ko, vf, out);
}

// Round 7
// 304.691 us; speedup vs baseline: 1.0940x; 1.0940x over previous
//
#include <hip/hip_runtime.h>

typedef __bf16 bf16;
typedef __bf16 bf16x8 __attribute__((ext_vector_type(8)));
typedef __bf16 bf16x4 __attribute__((ext_vector_type(4)));
typedef _Float16 f16x4 __attribute__((ext_vector_type(4)));
typedef _Float16 f16x8 __attribute__((ext_vector_type(8)));
typedef float  f32x4  __attribute__((ext_vector_type(4)));

#define LOG2E 1.44269504088896340736f
#define SCQ (0.125f * LOG2E)

__device__ __forceinline__ void async16(const void* g, void* l) {
  __builtin_amdgcn_global_load_lds(
      (const __attribute__((address_space(1))) unsigned int*)g,
      (__attribute__((address_space(3))) unsigned int*)l, 16, 0, 0);
}

__device__ __forceinline__ f32x4 mfma_bf16(bf16x8 a, bf16x8 b, f32x4 c) {
  return __builtin_amdgcn_mfma_f32_16x16x32_bf16(a, b, c, 0, 0, 0);
}
__device__ __forceinline__ f32x4 mfma_f16k16(f16x4 a, f16x4 b, f32x4 c) {
  return __builtin_amdgcn_mfma_f32_16x16x16f16(a, b, c, 0, 0, 0);
}

// ------------- prep: fused activation cvt (fp32->bf16) + weight transpose -------
// grid (4352, 3): x<4096 -> cvt 8 elems/thread of activation z;
//                 x>=4096 -> 64x64 transpose tile of W_z into Wt bf16.
__global__ __launch_bounds__(256) void prep(const float* __restrict__ q,
                                            const float* __restrict__ k,
                                            const float* __restrict__ v,
                                            const float* __restrict__ W0,
                                            const float* __restrict__ W1,
                                            const float* __restrict__ W2,
                                            bf16* __restrict__ actb,
                                            bf16* __restrict__ Wt) {
  __shared__ float t[64 * 69];
  const int z = blockIdx.y, tid = threadIdx.x;
  if (blockIdx.x < 4096) {
    const float* in = z == 0 ? q : (z == 1 ? k : v);
    bf16* o = actb + (size_t)z * 8388608;
    int i = blockIdx.x * 256 + tid;
    const float4* p = (const float4*)in;
    float4 a = p[i * 2], c = p[i * 2 + 1];
    bf16x8 r;
    r[0] = (bf16)a.x; r[1] = (bf16)a.y; r[2] = (bf16)a.z; r[3] = (bf16)a.w;
    r[4] = (bf16)c.x; r[5] = (bf16)c.y; r[6] = (bf16)c.z; r[7] = (bf16)c.w;
    ((bf16x8*)o)[i] = r;
  } else {
    const float* W = z == 0 ? W0 : (z == 1 ? W1 : W2);
    bf16* O = Wt + (size_t)z * (1024 * 1024);
    int lin = blockIdx.x - 4096;
    int k0 = (lin & 15) * 64, n0 = (lin >> 4) * 64;
    int r0 = tid >> 4, c0 = (tid & 15) * 4;
#pragma unroll
    for (int rr = 0; rr < 4; rr++) {
      int kk = r0 + rr * 16;
      float4 vv = *(const float4*)(W + (k0 + kk) * 1024 + n0 + c0);
      t[kk * 69 + c0 + 0] = vv.x; t[kk * 69 + c0 + 1] = vv.y;
      t[kk * 69 + c0 + 2] = vv.z; t[kk * 69 + c0 + 3] = vv.w;
    }
    __syncthreads();
#pragma unroll
    for (int rr = 0; rr < 4; rr++) {
      int n = r0 + rr * 16;
      bf16x4 o;
#pragma unroll
      for (int j = 0; j < 4; j++) o[j] = (bf16)t[(c0 + j) * 69 + n];
      *(bf16x4*)(O + (n0 + n) * 1024 + k0 + c0) = o;
    }
  }
}

// ---------------- batched projection GEMM, 128x128, m97 config ----------------
// grid (64, 8, 3); two-barrier K-loop; 3 blocks/CU via __launch_bounds__(256,3).
// z=0: qo = (A*Wq+bq)*SCQ bf16 [m][n]; z=1: ko = A*Wk+bk bf16 [m][n];
// z=2: vf = A*Wv+bv f16, paired PV-fragment order:
//      off = ((((b*16+h)*32+kvb64)*8 + mt*2+np)*64 + lane)*8
//      element (kv,d): kvb64=kv>>6, mt=(kv>>4)&3, lane=((kv>>2)&3)*16+(d&15),
//      slot = ((d>>4)&1)*4 + (kv&3), np=(d>>5)&1.
__global__ __launch_bounds__(256, 3) void gemm_qkv(const bf16* __restrict__ Act,
                                                   const bf16* __restrict__ Wt,
                                                   const float* __restrict__ b0,
                                                   const float* __restrict__ b1,
                                                   const float* __restrict__ b2,
                                                   bf16* __restrict__ qo,
                                                   bf16* __restrict__ ko,
                                                   _Float16* __restrict__ vf) {
  __shared__ bf16 smem[16384];          // sA 8192 | sB 8192 (32 KB)
  bf16* sA = smem;
  bf16* sB = smem + 8192;
  const int tid = threadIdx.x;
  const int wave = tid >> 6, lane = tid & 63;
  const int quad = lane >> 4, l15 = lane & 15;
  const int z = blockIdx.z;
  const int m0 = blockIdx.x * 128, n0 = blockIdx.y * 128;
  const bf16* A = Act + (size_t)z * 8388608;
  const bf16* Bt = Wt + (size_t)z * 1048576;
  const float* bias = z == 0 ? b0 : (z == 1 ? b1 : b2);

  const bf16* ap[4]; const bf16* bp[4]; int lo[4];
#pragma unroll
  for (int i = 0; i < 4; i++) {
    int g = wave * 256 + i * 64 + lane;
    int row = g >> 3, jl = (g & 7) ^ (row & 7);
    ap[i] = A + (m0 + row) * 1024 + jl * 8;
    bp[i] = Bt + (n0 + row) * 1024 + jl * 8;
    lo[i] = (wave * 256 + i * 64) * 8;
  }
  const int wm = (wave & 1) * 64, wn = (wave >> 1) * 64;
  f32x4 acc[4][4] = {};

  for (int kt = 0; kt < 16; kt++) {
    const int ko_ = kt * 64;
#pragma unroll
    for (int i = 0; i < 4; i++) async16(ap[i] + ko_, sA + lo[i]);
#pragma unroll
    for (int i = 0; i < 4; i++) async16(bp[i] + ko_, sB + lo[i]);
    __syncthreads();
#pragma unroll
    for (int ks = 0; ks < 2; ks++) {
      bf16x8 af[4], bv[4];
#pragma unroll
      for (int mt = 0; mt < 4; mt++) {
        int m = wm + mt * 16 + l15;
        int ph = (ks * 4 + quad) ^ (m & 7);
        af[mt] = *(const bf16x8*)(sA + m * 64 + ph * 8);
      }
#pragma unroll
      for (int nt = 0; nt < 4; nt++) {
        int n = wn + nt * 16 + l15;
        int ph = (ks * 4 + quad) ^ (n & 7);
        bv[nt] = *(const bf16x8*)(sB + n * 64 + ph * 8);
      }
#pragma unroll
      for (int mt = 0; mt < 4; mt++)
#pragma unroll
        for (int nt = 0; nt < 4; nt++)
          acc[mt][nt] = mfma_bf16(af[mt], bv[nt], acc[mt][nt]);
    }
    __syncthreads();
  }

  if (z != 2) {
    bf16* O = z == 0 ? qo : ko;
    const float sc = z == 0 ? SCQ : 1.0f;
#pragma unroll
    for (int nt = 0; nt < 4; nt++) {
      int n = n0 + wn + nt * 16 + l15;
      float bc = bias[n];
#pragma unroll
      for (int mt = 0; mt < 4; mt++)
#pragma unroll
        for (int r = 0; r < 4; r++) {
          int m = m0 + wm + mt * 16 + quad * 4 + r;
          O[m * 1024 + n] = (bf16)((acc[mt][nt][r] + bc) * sc);
        }
    }
  } else {
    // paired fragment-order stores: {acc[mt][2k2], acc[mt][2k2+1]} -> one f16x8
    const int b = m0 >> 11, s0 = m0 & 2047;
    const int kvb64 = (s0 + wm) >> 6;
#pragma unroll
    for (int k2 = 0; k2 < 2; k2++) {
      int nn = n0 + wn + k2 * 32;        // 32-aligned: h fixed across pair
      int h = nn >> 6, np = (nn >> 5) & 1;
      float bc0 = bias[nn + l15];
      float bc1 = bias[nn + 16 + l15];
#pragma unroll
      for (int mt = 0; mt < 4; mt++) {
        f16x8 pk;
#pragma unroll
        for (int r = 0; r < 4; r++) {
          pk[r]     = (_Float16)(acc[mt][2 * k2][r] + bc0);
          pk[4 + r] = (_Float16)(acc[mt][2 * k2 + 1][r] + bc1);
        }
        size_t off = ((((size_t)(b * 16 + h) * 32 + kvb64) * 8 + (mt * 2 + np)) * 64 + lane) * 8;
        *(f16x8*)(vf + off) = pk;
      }
    }
  }
}

// ------------- flash attention (r4 structure): KV-128 single-buffer ------------
// Q pre-scaled bf16 [B,S,1024]; K bf16 [B,S,1024]; VF f16 paired-fragment order;
// Out fp32 [B,S,1024]. Q-tile 128 (wave owns 32 q). 48 KB LDS.
__global__ __launch_bounds__(256, 4) void attn(const bf16* __restrict__ Q,
                                               const bf16* __restrict__ K,
                                               const _Float16* __restrict__ VF,
                                               float* __restrict__ Out) {
  __shared__ bf16 sQ[8192];        // 128 x 64 (16 KB)
  __shared__ bf16 sK[8192];        // 128 x 64 (16 KB)
  __shared__ _Float16 sV[8192];    // 2 x paired-fragment 64-blocks (16 KB)
  const int tid = threadIdx.x;
  const int wave = tid >> 6, lane = tid & 63;
  const int quad = lane >> 4, l15 = lane & 15;
  const int q0 = blockIdx.x * 128, h = blockIdx.y, b = blockIdx.z;
  const bf16* Kbase = K + (size_t)(b * 2048) * 1024 + h * 64;
  const _Float16* Vbase = VF + (size_t)(b * 16 + h) * 131072;

  // stage Q + K/V block 0
#pragma unroll
  for (int i = 0; i < 4; i++) {
    int g = i * 256 + tid;
    int row = g >> 3, jl = (g & 7) ^ (row & 7);
    async16(Q + (size_t)(b * 2048 + q0 + row) * 1024 + h * 64 + jl * 8, sQ + g * 8);
    async16(Kbase + (size_t)row * 1024 + jl * 8, sK + g * 8);
    async16(Vbase + g * 8, sV + g * 8);
  }
  __syncthreads();

  // Q fragments (B-operand: lane=q, k=quad*8+j), wave owns q rows wave*32..+31
  bf16x8 qf[2][2];
#pragma unroll
  for (int qt2 = 0; qt2 < 2; qt2++)
#pragma unroll
    for (int ks = 0; ks < 2; ks++) {
      int m = wave * 32 + qt2 * 16 + l15;
      int ph = (ks * 4 + quad) ^ (l15 & 7);
      qf[qt2][ks] = *(const bf16x8*)(sQ + m * 64 + ph * 8);
    }

  f32x4 oaccT[2][4] = {};    // [qt2][dt] : O^T tile, row=d(quad*4+r), col=q(l15)
  float ls[2] = {0.f, 0.f};
  const int ph0 = quad ^ (l15 & 7), ph1 = (4 + quad) ^ (l15 & 7);

  for (int kvb = 0; kvb < 16; kvb++) {
#pragma unroll
    for (int t = 0; t < 8; t++) {
      int row = t * 16 + l15;
      bf16x8 kf0 = *(const bf16x8*)(sK + row * 64 + ph0 * 8);
      bf16x8 kf1 = *(const bf16x8*)(sK + row * 64 + ph1 * 8);
      f32x4 st0 = {}, st1 = {};
      st0 = mfma_bf16(kf0, qf[0][0], st0);
      st0 = mfma_bf16(kf1, qf[0][1], st0);
      st1 = mfma_bf16(kf0, qf[1][0], st1);
      st1 = mfma_bf16(kf1, qf[1][1], st1);
      f16x4 pf0, pf1;
#pragma unroll
      for (int r = 0; r < 4; r++) {
        float p0 = __builtin_amdgcn_exp2f(st0[r]);
        float p1 = __builtin_amdgcn_exp2f(st1[r]);
        ls[0] += p0; ls[1] += p1;
        pf0[r] = (_Float16)p0; pf1[r] = (_Float16)p1;
      }
      const _Float16* sVt = sV + (t >> 2) * 4096 + (t & 3) * 1024;
#pragma unroll
      for (int np = 0; np < 2; np++) {
        f16x8 va2 = *(const f16x8*)(sVt + np * 512 + lane * 8);
        f16x4 lo = __builtin_shufflevector(va2, va2, 0, 1, 2, 3);
        f16x4 hi = __builtin_shufflevector(va2, va2, 4, 5, 6, 7);
        oaccT[0][2 * np]     = mfma_f16k16(lo, pf0, oaccT[0][2 * np]);
        oaccT[0][2 * np + 1] = mfma_f16k16(hi, pf0, oaccT[0][2 * np + 1]);
        oaccT[1][2 * np]     = mfma_f16k16(lo, pf1, oaccT[1][2 * np]);
        oaccT[1][2 * np + 1] = mfma_f16k16(hi, pf1, oaccT[1][2 * np + 1]);
      }
    }
    __syncthreads();
    if (kvb < 15) {
      int kn = (kvb + 1) * 128;
#pragma unroll
      for (int i = 0; i < 4; i++) {
        int g = i * 256 + tid;
        int row = g >> 3, jl = (g & 7) ^ (row & 7);
        async16(Kbase + (size_t)(kn + row) * 1024 + jl * 8, sK + g * 8);
        async16(Vbase + (kvb + 1) * 8192 + g * 8, sV + g * 8);
      }
      __syncthreads();
    }
  }

  // ---- epilogue: reduce l across quads, scale, store fp32 ----
#pragma unroll
  for (int qt2 = 0; qt2 < 2; qt2++) {
    float l = ls[qt2];
    l += __shfl_xor(l, 16);
    l += __shfl_xor(l, 32);
    float inv = 1.f / l;
    int qrow = b * 2048 + q0 + wave * 32 + qt2 * 16 + l15;
#pragma unroll
    for (int dt = 0; dt < 4; dt++) {
      float4 v;
      v.x = oaccT[qt2][dt][0] * inv;
      v.y = oaccT[qt2][dt][1] * inv;
      v.z = oaccT[qt2][dt][2] * inv;
      v.w = oaccT[qt2][dt][3] * inv;
      *(float4*)(Out + (size_t)qrow * 1024 + h * 64 + dt * 16 + quad * 4) = v;
    }
  }
}

extern "C" void kernel_launch(void* const* d_in, const int* in_sizes, int n_in,
                              void* d_out, int out_size, void* d_ws, size_t ws_size,
                              hipStream_t stream) {
  const float* key   = (const float*)d_in[0];
  const float* value = (const float*)d_in[1];
  const float* query = (const float*)d_in[2];
  const float* Wq = (const float*)d_in[3];
  const float* bq = (const float*)d_in[4];
  const float* Wk = (const float*)d_in[5];
  const float* bk = (const float*)d_in[6];
  const float* Wv = (const float*)d_in[7];
  const float* bv = (const float*)d_in[8];
  float* out = (float*)d_out;

  char* ws = (char*)d_ws;
  bf16* actb   = (bf16*)(ws);                       // 48 MB: [query|key|value] bf16
  bf16* wt     = (bf16*)(ws + 50331648);            // 6 MB: Wq^T,Wk^T,Wv^T
  bf16* qo     = (bf16*)(ws + 56623104);            // 16 MB (pre-scaled)
  bf16* ko     = (bf16*)(ws + 73400320);            // 16 MB
  _Float16* vf = (_Float16*)(ws + 90177536);        // 16 MB paired-fragment order
  (void)in_sizes; (void)n_in; (void)out_size; (void)ws_size;

  prep<<<dim3(4352, 3), 256, 0, stream>>>(query, key, value, Wq, Wk, Wv, actb, wt);
  gemm_qkv<<<dim3(64, 8, 3), 256, 0, stream>>>(actb, wt, bq, bk, bv, qo, ko, vf);
  attn<<<dim3(16, 16, 4), 256, 0, stream>>>(qo, ko, vf, out);
}

// Round 9
// 301.988 us; speedup vs baseline: 1.1038x; 1.0089x over previous
//
#include <hip/hip_runtime.h>

typedef __bf16 bf16;
typedef __bf16 bf16x8 __attribute__((ext_vector_type(8)));
typedef __bf16 bf16x4 __attribute__((ext_vector_type(4)));
typedef _Float16 f16x2 __attribute__((ext_vector_type(2)));
typedef _Float16 f16x4 __attribute__((ext_vector_type(4)));
typedef _Float16 f16x8 __attribute__((ext_vector_type(8)));
typedef __fp16 h16x2 __attribute__((ext_vector_type(2)));
typedef __fp16 h16x4 __attribute__((ext_vector_type(4)));
typedef float  f32x4  __attribute__((ext_vector_type(4)));
typedef float  f32x16 __attribute__((ext_vector_type(16)));

#define LOG2E 1.44269504088896340736f
#define SCQ (0.125f * LOG2E)

__device__ __forceinline__ void async16(const void* g, void* l) {
  __builtin_amdgcn_global_load_lds(
      (const __attribute__((address_space(1))) unsigned int*)g,
      (__attribute__((address_space(3))) unsigned int*)l, 16, 0, 0);
}

__device__ __forceinline__ f32x4 mfma_bf16(bf16x8 a, bf16x8 b, f32x4 c) {
  return __builtin_amdgcn_mfma_f32_16x16x32_bf16(a, b, c, 0, 0, 0);
}
__device__ __forceinline__ f32x16 mfma32_bf16(bf16x8 a, bf16x8 b, f32x16 c) {
  return __builtin_amdgcn_mfma_f32_32x32x16_bf16(a, b, c, 0, 0, 0);
}
__device__ __forceinline__ f32x16 mfma32x8_f16(f16x4 a, f16x4 b, f32x16 c) {
  return __builtin_amdgcn_mfma_f32_32x32x8f16(a, b, c, 0, 0, 0);
}

// ------------- prep: fused activation cvt (fp32->bf16) + weight transpose -------
__global__ __launch_bounds__(256) void prep(const float* __restrict__ q,
                                            const float* __restrict__ k,
                                            const float* __restrict__ v,
                                            const float* __restrict__ W0,
                                            const float* __restrict__ W1,
                                            const float* __restrict__ W2,
                                            bf16* __restrict__ actb,
                                            bf16* __restrict__ Wt) {
  __shared__ float t[64 * 69];
  const int z = blockIdx.y, tid = threadIdx.x;
  if (blockIdx.x < 4096) {
    const float* in = z == 0 ? q : (z == 1 ? k : v);
    bf16* o = actb + (size_t)z * 8388608;
    int i = blockIdx.x * 256 + tid;
    const float4* p = (const float4*)in;
    float4 a = p[i * 2], c = p[i * 2 + 1];
    bf16x8 r;
    r[0] = (bf16)a.x; r[1] = (bf16)a.y; r[2] = (bf16)a.z; r[3] = (bf16)a.w;
    r[4] = (bf16)c.x; r[5] = (bf16)c.y; r[6] = (bf16)c.z; r[7] = (bf16)c.w;
    ((bf16x8*)o)[i] = r;
  } else {
    const float* W = z == 0 ? W0 : (z == 1 ? W1 : W2);
    bf16* O = Wt + (size_t)z * (1024 * 1024);
    int lin = blockIdx.x - 4096;
    int k0 = (lin & 15) * 64, n0 = (lin >> 4) * 64;
    int r0 = tid >> 4, c0 = (tid & 15) * 4;
#pragma unroll
    for (int rr = 0; rr < 4; rr++) {
      int kk = r0 + rr * 16;
      float4 vv = *(const float4*)(W + (k0 + kk) * 1024 + n0 + c0);
      t[kk * 69 + c0 + 0] = vv.x; t[kk * 69 + c0 + 1] = vv.y;
      t[kk * 69 + c0 + 2] = vv.z; t[kk * 69 + c0 + 3] = vv.w;
    }
    __syncthreads();
#pragma unroll
    for (int rr = 0; rr < 4; rr++) {
      int n = r0 + rr * 16;
      bf16x4 o;
#pragma unroll
      for (int j = 0; j < 4; j++) o[j] = (bf16)t[(c0 + j) * 69 + n];
      *(bf16x4*)(O + (n0 + n) * 1024 + k0 + c0) = o;
    }
  }
}

// ---------------- batched projection GEMM, 128x128, m97 config ----------------
// z=0: qo = (A*Wq+bq)*SCQ bf16 [m][n]; z=1: ko = A*Wk+bk bf16 [m][n];
// z=2: vf = A*Wv+bv f16, 32x32x8-A-fragment order:
//      element (kv,d) of head hh: t32=kv>>5(in 128-blk), u=(kv>>4)&1,
//      w=(kv>>3)&1, hl=(kv>>2)&1, j=kv&3; fi=(t32*2+u)*2+db, db=(d>>5)&1;
//      lane=32*hl+(d&31); slot=w*4+j.
//      off = (((b*16+hh)*16+kvb)*16+fi)*512 + lane*8 + w*4 + j
__global__ __launch_bounds__(256, 3) void gemm_qkv(const bf16* __restrict__ Act,
                                                   const bf16* __restrict__ Wt,
                                                   const float* __restrict__ b0,
                                                   const float* __restrict__ b1,
                                                   const float* __restrict__ b2,
                                                   bf16* __restrict__ qo,
                                                   bf16* __restrict__ ko,
                                                   _Float16* __restrict__ vf) {
  __shared__ bf16 smem[16384];          // sA 8192 | sB 8192 (32 KB)
  bf16* sA = smem;
  bf16* sB = smem + 8192;
  const int tid = threadIdx.x;
  const int wave = tid >> 6, lane = tid & 63;
  const int quad = lane >> 4, l15 = lane & 15;
  const int z = blockIdx.z;
  const int m0 = blockIdx.x * 128, n0 = blockIdx.y * 128;
  const bf16* A = Act + (size_t)z * 8388608;
  const bf16* Bt = Wt + (size_t)z * 1048576;
  const float* bias = z == 0 ? b0 : (z == 1 ? b1 : b2);

  const bf16* ap[4]; const bf16* bp[4]; int lo[4];
#pragma unroll
  for (int i = 0; i < 4; i++) {
    int g = wave * 256 + i * 64 + lane;
    int row = g >> 3, jl = (g & 7) ^ (row & 7);
    ap[i] = A + (m0 + row) * 1024 + jl * 8;
    bp[i] = Bt + (n0 + row) * 1024 + jl * 8;
    lo[i] = (wave * 256 + i * 64) * 8;
  }
  const int wm = (wave & 1) * 64, wn = (wave >> 1) * 64;
  f32x4 acc[4][4] = {};

  for (int kt = 0; kt < 16; kt++) {
    const int ko_ = kt * 64;
#pragma unroll
    for (int i = 0; i < 4; i++) async16(ap[i] + ko_, sA + lo[i]);
#pragma unroll
    for (int i = 0; i < 4; i++) async16(bp[i] + ko_, sB + lo[i]);
    __syncthreads();
#pragma unroll
    for (int ks = 0; ks < 2; ks++) {
      bf16x8 af[4], bv[4];
#pragma unroll
      for (int mt = 0; mt < 4; mt++) {
        int m = wm + mt * 16 + l15;
        int ph = (ks * 4 + quad) ^ (m & 7);
        af[mt] = *(const bf16x8*)(sA + m * 64 + ph * 8);
      }
#pragma unroll
      for (int nt = 0; nt < 4; nt++) {
        int n = wn + nt * 16 + l15;
        int ph = (ks * 4 + quad) ^ (n & 7);
        bv[nt] = *(const bf16x8*)(sB + n * 64 + ph * 8);
      }
#pragma unroll
      for (int mt = 0; mt < 4; mt++)
#pragma unroll
        for (int nt = 0; nt < 4; nt++)
          acc[mt][nt] = mfma_bf16(af[mt], bv[nt], acc[mt][nt]);
    }
    __syncthreads();
  }

  if (z != 2) {
    bf16* O = z == 0 ? qo : ko;
    const float sc = z == 0 ? SCQ : 1.0f;
#pragma unroll
    for (int nt = 0; nt < 4; nt++) {
      int n = n0 + wn + nt * 16 + l15;
      float bc = bias[n];
#pragma unroll
      for (int mt = 0; mt < 4; mt++)
#pragma unroll
        for (int r = 0; r < 4; r++) {
          int m = m0 + wm + mt * 16 + quad * 4 + r;
          O[m * 1024 + n] = (bf16)((acc[mt][nt][r] + bc) * sc);
        }
    }
  } else {
    // 32x32x8 A-fragment-order stores (see header comment)
    const int b = m0 >> 11, s0 = m0 & 2047;
    const int kvb = s0 >> 7;
    const int mtg0 = (wave & 1) * 4;
    const int w = quad >> 1, hl = quad & 1;
#pragma unroll
    for (int nt = 0; nt < 4; nt++) {
      int n = n0 + wn + nt * 16;
      int hh = n >> 6, db = (n >> 5) & 1;
      int lanep = hl * 32 + (nt & 1) * 16 + l15;
      float bc = bias[n + l15];
#pragma unroll
      for (int mt = 0; mt < 4; mt++) {
        int fi = (mtg0 + mt) * 2 + db;
        f16x4 pk;
#pragma unroll
        for (int r = 0; r < 4; r++) pk[r] = (_Float16)(acc[mt][nt][r] + bc);
        size_t off = ((((size_t)(b * 16 + hh) * 16 + kvb) * 16 + fi) * 512)
                     + lanep * 8 + w * 4;
        *(f16x4*)(vf + off) = pk;
      }
    }
  }
}

// ------------- flash attention, 32x32 core, KV-128 single-buffer ------------
// Q pre-scaled bf16 [B,S,1024]; K bf16 [B,S,1024]; VF f16 32x32x8-frag order;
// Out fp32 [B,S,1024]. Q-tile 128 (wave owns 32 q rows). 48 KB LDS.
// S^T = K·Q^T via mfma_32x32x16_bf16; its C-layout == B-operand layout of
// mfma_32x32x8_f16 (slices of 8 kv = reg quads), so P feeds PV directly.
__global__ __launch_bounds__(256, 3) void attn(const bf16* __restrict__ Q,
                                               const bf16* __restrict__ K,
                                               const _Float16* __restrict__ VF,
                                               float* __restrict__ Out) {
  __shared__ bf16 sQ[8192];        // 128 x 64 swizzled (16 KB)
  __shared__ bf16 sK[8192];        // 128 x 64 swizzled (16 KB)
  __shared__ _Float16 sV[8192];    // 16 frags x 64 lanes x 8 (16 KB)
  const int tid = threadIdx.x;
  const int wave = tid >> 6, lane = tid & 63;
  const int l31 = lane & 31, hl = lane >> 5;
  const int q0 = blockIdx.x * 128, hh = blockIdx.y, b = blockIdx.z;
  const bf16* Kbase = K + (size_t)(b * 2048) * 1024 + hh * 64;
  const _Float16* Vbase = VF + (size_t)(b * 16 + hh) * 131072;

  // stage Q + K/V block 0
#pragma unroll
  for (int i = 0; i < 4; i++) {
    int g = i * 256 + tid;
    int row = g >> 3, jl = (g & 7) ^ (row & 7);
    async16(Q + (size_t)(b * 2048 + q0 + row) * 1024 + hh * 64 + jl * 8, sQ + g * 8);
    async16(Kbase + (size_t)row * 1024 + jl * 8, sK + g * 8);
    async16(Vbase + g * 8, sV + g * 8);
  }
  __syncthreads();

  // Q fragments (B-operand of 32x32x16: n=q=lane&31, k=d=16i+8*hl+j)
  bf16x8 qf[4];
  {
    int rowq = wave * 32 + l31, rx = rowq & 7;
#pragma unroll
    for (int i = 0; i < 4; i++)
      qf[i] = *(const bf16x8*)(sQ + rowq * 64 + ((2 * i + hl) ^ rx) * 8);
  }

  f32x16 oacc[2] = {};    // O^T: [db] rows d = 32db + (reg&3)+8(reg>>2)+4hl, col q
  float ls = 0.f;

  for (int kvb = 0; kvb < 16; kvb++) {
#pragma unroll
    for (int t32 = 0; t32 < 4; t32++) {
      // ---- S^T (32 kv x 32 q): A=K rows kv, B=Q^T ----
      int rowk = t32 * 32 + l31, rx = rowk & 7;
      const bf16* kr = sK + rowk * 64;
      f32x16 st = {};
#pragma unroll
      for (int i = 0; i < 4; i++) {
        bf16x8 kf = *(const bf16x8*)(kr + ((2 * i + hl) ^ rx) * 8);
        st = mfma32_bf16(kf, qf[i], st);
      }
      // ---- exp2 + pack to f16 (B-operand of 32x32x8 = C-layout, direct) ----
      f16x4 pf[4];
      float ps = 0.f;
#pragma unroll
      for (int s = 0; s < 4; s++) {
        float p0 = __builtin_amdgcn_exp2f(st[4 * s + 0]);
        float p1 = __builtin_amdgcn_exp2f(st[4 * s + 1]);
        float p2 = __builtin_amdgcn_exp2f(st[4 * s + 2]);
        float p3 = __builtin_amdgcn_exp2f(st[4 * s + 3]);
        ps += (p0 + p1) + (p2 + p3);
        h16x2 c0 = __builtin_amdgcn_cvt_pkrtz(p0, p1);
        h16x2 c1 = __builtin_amdgcn_cvt_pkrtz(p2, p3);
        h16x4 cc = __builtin_shufflevector(c0, c1, 0, 1, 2, 3);
        pf[s] = __builtin_bit_cast(f16x4, cc);
      }
      ls += ps;
      // ---- O^T += V^T P^T : 8 x mfma_32x32x8_f16 ----
#pragma unroll
      for (int u = 0; u < 2; u++)
#pragma unroll
        for (int db = 0; db < 2; db++) {
          f16x8 va2 = *(const f16x8*)(sV + ((t32 * 4 + u * 2 + db) * 64 + lane) * 8);
          f16x4 vlo = __builtin_shufflevector(va2, va2, 0, 1, 2, 3);
          f16x4 vhi = __builtin_shufflevector(va2, va2, 4, 5, 6, 7);
          oacc[db] = mfma32x8_f16(vlo, pf[2 * u], oacc[db]);
          oacc[db] = mfma32x8_f16(vhi, pf[2 * u + 1], oacc[db]);
        }
    }
    __syncthreads();
    if (kvb < 15) {
      int kn = (kvb + 1) * 128;
#pragma unroll
      for (int i = 0; i < 4; i++) {
        int g = i * 256 + tid;
        int row = g >> 3, jl = (g & 7) ^ (row & 7);
        async16(Kbase + (size_t)(kn + row) * 1024 + jl * 8, sK + g * 8);
        async16(Vbase + (kvb + 1) * 8192 + g * 8, sV + g * 8);
      }
      __syncthreads();
    }
  }

  // ---- epilogue: l = own-half + other-half, scale, store fp32 ----
  ls += __shfl_xor(ls, 32);
  float inv = 1.f / ls;
  int qrow = b * 2048 + q0 + wave * 32 + l31;
  float* orow = Out + (size_t)qrow * 1024 + hh * 64;
#pragma unroll
  for (int db = 0; db < 2; db++)
#pragma unroll
    for (int rg = 0; rg < 4; rg++) {
      float4 v;
      v.x = oacc[db][4 * rg + 0] * inv;
      v.y = oacc[db][4 * rg + 1] * inv;
      v.z = oacc[db][4 * rg + 2] * inv;
      v.w = oacc[db][4 * rg + 3] * inv;
      *(float4*)(orow + db * 32 + rg * 8 + 4 * hl) = v;
    }
}

extern "C" void kernel_launch(void* const* d_in, const int* in_sizes, int n_in,
                              void* d_out, int out_size, void* d_ws, size_t ws_size,
                              hipStream_t stream) {
  const float* key   = (const float*)d_in[0];
  const float* value = (const float*)d_in[1];
  const float* query = (const float*)d_in[2];
  const float* Wq = (const float*)d_in[3];
  const float* bq = (const float*)d_in[4];
  const float* Wk = (const float*)d_in[5];
  const float* bk = (const float*)d_in[6];
  const float* Wv = (const float*)d_in[7];
  const float* bv = (const float*)d_in[8];
  float* out = (float*)d_out;

  char* ws = (char*)d_ws;
  bf16* actb   = (bf16*)(ws);                       // 48 MB: [query|key|value] bf16
  bf16* wt     = (bf16*)(ws + 50331648);            // 6 MB: Wq^T,Wk^T,Wv^T
  bf16* qo     = (bf16*)(ws + 56623104);            // 16 MB (pre-scaled)
  bf16* ko     = (bf16*)(ws + 73400320);            // 16 MB
  _Float16* vf = (_Float16*)(ws + 90177536);        // 16 MB 32x32x8-frag order
  (void)in_sizes; (void)n_in; (void)out_size; (void)ws_size;

  prep<<<dim3(4352, 3), 256, 0, stream>>>(query, key, value, Wq, Wk, Wv, actb, wt);
  gemm_qkv<<<dim3(64, 8, 3), 256, 0, stream>>>(actb, wt, bq, bk, bv, qo, ko, vf);
  attn<<<dim3(16, 16, 4), 256, 0, stream>>>(qo, ko, vf, out);
}